// Round 1
// baseline (906.291 us; speedup 1.0000x reference)
//
#include <hip/hip_runtime.h>
#include <hip/hip_bf16.h>
#include <math.h>

constexpr int N_NODES = 50000;
constexpr int N_EDGES = 850000;
constexpr int HDIM = 128;   // H*D
constexpr int NHEAD = 4;
constexpr int DHEAD = 32;

// ---------------------------------------------------------------- CSR build
__global__ void k_hist(const int* __restrict__ dst, int* __restrict__ deg) {
    int i = blockIdx.x * blockDim.x + threadIdx.x;
    if (i < N_EDGES) atomicAdd(&deg[dst[i]], 1);
}

// single block, 1024 threads: exclusive scan of deg -> rowstart, cursor
__global__ void k_scan(const int* __restrict__ deg, int* __restrict__ rowstart,
                       int* __restrict__ cursor) {
    __shared__ int sm[1024];
    __shared__ int s_carry;
    if (threadIdx.x == 0) s_carry = 0;
    __syncthreads();
    for (int base = 0; base < N_NODES; base += 1024) {
        int i = base + threadIdx.x;
        int v = (i < N_NODES) ? deg[i] : 0;
        sm[threadIdx.x] = v;
        __syncthreads();
        for (int off = 1; off < 1024; off <<= 1) {
            int t = (threadIdx.x >= off) ? sm[threadIdx.x - off] : 0;
            __syncthreads();
            sm[threadIdx.x] += t;
            __syncthreads();
        }
        int carry = s_carry;
        int excl = carry + sm[threadIdx.x] - v;
        if (i < N_NODES) { rowstart[i] = excl; cursor[i] = excl; }
        __syncthreads();
        if (threadIdx.x == 1023) s_carry = carry + sm[1023];
        __syncthreads();
    }
    if (threadIdx.x == 0) rowstart[N_NODES] = s_carry;
}

__global__ void k_scatter(const int* __restrict__ src, const int* __restrict__ dst,
                          int* __restrict__ cursor, int* __restrict__ esrc) {
    int i = blockIdx.x * blockDim.x + threadIdx.x;
    if (i < N_EDGES) {
        int p = atomicAdd(&cursor[dst[i]], 1);
        esrc[p] = src[i];
    }
}

// ---------------------------------------------------------------- embed gather
__global__ void k_embed(const int* __restrict__ x, const float* __restrict__ embed,
                        float* __restrict__ h) {
    int i = blockIdx.x * blockDim.x + threadIdx.x;
    if (i < N_NODES * HDIM) {
        int n = i >> 7, c = i & 127;
        h[i] = embed[x[n] * HDIM + c];
    }
}

// ---------------------------------------------------------------- GEMM: feat = h @ W  (NxK=Nx128, 128x128)
// block: 256 thr, 32 nodes/block, 4x4 micro-tile per thread. h staged transposed in LDS.
__global__ void k_gemm(const float* __restrict__ h, const float* __restrict__ W,
                       float* __restrict__ feat) {
    __shared__ __align__(16) float hsT[128][36];  // +4 pad: bank-shift, keeps float4 alignment
    int tid = threadIdx.x;
    int nbase = blockIdx.x * 32;
    for (int i = tid; i < 32 * 128; i += 256) {
        int r = i >> 7, c = i & 127;
        int n = nbase + r;
        hsT[c][r] = (n < N_NODES) ? h[n * HDIM + c] : 0.f;
    }
    __syncthreads();
    int c4 = (tid & 31) * 4;
    int n4 = (tid >> 5) * 4;
    float acc[4][4] = {};
#pragma unroll 4
    for (int k = 0; k < 128; k++) {
        float4 w = *reinterpret_cast<const float4*>(&W[k * HDIM + c4]);
        float4 hv = *reinterpret_cast<const float4*>(&hsT[k][n4]);
        float wv[4] = {w.x, w.y, w.z, w.w};
        float hh[4] = {hv.x, hv.y, hv.z, hv.w};
#pragma unroll
        for (int i = 0; i < 4; i++)
#pragma unroll
            for (int j = 0; j < 4; j++) acc[i][j] += hh[i] * wv[j];
    }
#pragma unroll
    for (int i = 0; i < 4; i++) {
        int n = nbase + n4 + i;
        if (n < N_NODES) {
            float4 o = make_float4(acc[i][0], acc[i][1], acc[i][2], acc[i][3]);
            *reinterpret_cast<float4*>(&feat[n * HDIM + c4]) = o;
        }
    }
}

// ---------------------------------------------------------------- el/er: one wave per node
__global__ void k_attn_coef(const float* __restrict__ feat, const float* __restrict__ al,
                            const float* __restrict__ ar, float* __restrict__ el,
                            float* __restrict__ er) {
    int v = (blockIdx.x * blockDim.x + threadIdx.x) >> 6;
    int lane = threadIdx.x & 63;
    if (v >= N_NODES) return;
    int c = lane * 2;
    int hd = lane >> 4;
    int d = c & 31;
    float2 f = *reinterpret_cast<const float2*>(&feat[v * HDIM + c]);
    float pl = f.x * al[hd * 32 + d] + f.y * al[hd * 32 + d + 1];
    float pr = f.x * ar[hd * 32 + d] + f.y * ar[hd * 32 + d + 1];
#pragma unroll
    for (int off = 1; off < 16; off <<= 1) {
        pl += __shfl_xor(pl, off, 64);
        pr += __shfl_xor(pr, off, 64);
    }
    if ((lane & 15) == 0) {
        el[v * 4 + hd] = pl;
        er[v * 4 + hd] = pr;
    }
}

// ---------------------------------------------------------------- aggregation: one wave per dst node
// online softmax over incoming edges; fused residual + ELU + snorm. Writes h in place (own row only).
__global__ void k_aggregate(const float* __restrict__ feat, const float* __restrict__ el,
                            const float* __restrict__ er, const int* __restrict__ rowstart,
                            const int* __restrict__ esrc, const float* __restrict__ snorm_n,
                            float* __restrict__ h, int residual_act) {
    int v = (blockIdx.x * blockDim.x + threadIdx.x) >> 6;
    int lane = threadIdx.x & 63;
    if (v >= N_NODES) return;
    int c = lane * 2;
    int hd = lane >> 4;
    float erv = er[v * 4 + hd];
    int e0 = rowstart[v], e1 = rowstart[v + 1];
    float m = -INFINITY, s = 0.f, a0 = 0.f, a1 = 0.f;
    for (int i = e0; i < e1; i++) {
        int sidx = esrc[i];
        float e = el[sidx * 4 + hd] + erv;
        e = (e >= 0.f) ? e : 0.2f * e;  // leaky_relu 0.2
        float mnew = fmaxf(m, e);
        float alpha = __expf(m - mnew);  // exp(-inf)=0 handles first iter
        float w = __expf(e - mnew);
        s = s * alpha + w;
        a0 = a0 * alpha; a1 = a1 * alpha;
        float2 f = *reinterpret_cast<const float2*>(&feat[sidx * HDIM + c]);
        a0 += f.x * w; a1 += f.y * w;
        m = mnew;
    }
    float inv = 1.f / s;  // deg>=1 (self loops) so s>0
    a0 *= inv; a1 *= inv;
    if (residual_act) {
        float2 hr = *reinterpret_cast<const float2*>(&h[v * HDIM + c]);
        a0 += hr.x; a1 += hr.y;
        a0 = (a0 > 0.f) ? a0 : expm1f(a0);  // elu
        a1 = (a1 > 0.f) ? a1 : expm1f(a1);
    }
    float sn = snorm_n[v];
    a0 *= sn; a1 *= sn;
    *reinterpret_cast<float2*>(&h[v * HDIM + c]) = make_float2(a0, a1);
}

// ---------------------------------------------------------------- BatchNorm
__global__ void k_bn_stats(const float* __restrict__ h, double* __restrict__ sums) {
    int c = threadIdx.x;  // 128 threads: one feature each
    double s = 0.0, s2 = 0.0;
    for (int r = blockIdx.x; r < N_NODES; r += gridDim.x) {
        float v = h[r * HDIM + c];
        s += v;
        s2 += (double)v * v;
    }
    atomicAdd(&sums[c], s);
    atomicAdd(&sums[128 + c], s2);
}

__global__ void k_bn_final(const double* __restrict__ sums, const float* __restrict__ gamma,
                           const float* __restrict__ beta, float* __restrict__ scale,
                           float* __restrict__ shift) {
    int c = threadIdx.x;
    double mu = sums[c] / N_NODES;
    double var = sums[128 + c] / N_NODES - mu * mu;
    float sc = gamma[c] * rsqrtf((float)var + 1e-5f);
    scale[c] = sc;
    shift[c] = beta[c] - (float)mu * sc;
}

__global__ void k_bn_apply(float* __restrict__ h, const float* __restrict__ scale,
                           const float* __restrict__ shift) {
    int i = blockIdx.x * blockDim.x + threadIdx.x;  // over N*32 float4s
    if (i >= N_NODES * 32) return;
    int c4 = (i & 31) * 4;
    float4 v = reinterpret_cast<const float4*>(h)[i];
    float4 sc = *reinterpret_cast<const float4*>(&scale[c4]);
    float4 sh = *reinterpret_cast<const float4*>(&shift[c4]);
    float o0 = v.x * sc.x + sh.x, o1 = v.y * sc.y + sh.y;
    float o2 = v.z * sc.z + sh.z, o3 = v.w * sc.w + sh.w;
    o0 = (o0 > 0.f) ? o0 : expm1f(o0);
    o1 = (o1 > 0.f) ? o1 : expm1f(o1);
    o2 = (o2 > 0.f) ? o2 : expm1f(o2);
    o3 = (o3 > 0.f) ? o3 : expm1f(o3);
    reinterpret_cast<float4*>(h)[i] = make_float4(o0, o1, o2, o3);
}

// ---------------------------------------------------------------- classifier: relu(h@W1+b1)@W2+b2
// block: 256 thr = 4 waves, 16 nodes/block (4 per wave); lane j computes hidden j.
__global__ void k_classifier(const float* __restrict__ h, const float* __restrict__ W1,
                             const float* __restrict__ b1, const float* __restrict__ W2,
                             const float* __restrict__ b2, float* __restrict__ out) {
    __shared__ float hs[16][128];
    int tid = threadIdx.x;
    int nbase = blockIdx.x * 16;
    for (int i = tid; i < 16 * 128; i += 256) {
        int r = i >> 7, c = i & 127;
        int n = nbase + r;
        hs[r][c] = (n < N_NODES) ? h[n * HDIM + c] : 0.f;
    }
    __syncthreads();
    int j = tid & 63;
    int g = tid >> 6;  // wave id: nodes g*4 .. g*4+3
    float bj = b1[j];
    float acc[4] = {bj, bj, bj, bj};
    for (int k = 0; k < 128; k++) {
        float w = W1[k * 64 + j];
#pragma unroll
        for (int i = 0; i < 4; i++) acc[i] += hs[g * 4 + i][k] * w;
    }
    float w20 = W2[j * 2], w21 = W2[j * 2 + 1];
    float res[8];
#pragma unroll
    for (int i = 0; i < 4; i++) {
        float hid = fmaxf(acc[i], 0.f);
        res[2 * i] = hid * w20;
        res[2 * i + 1] = hid * w21;
    }
#pragma unroll
    for (int off = 1; off < 64; off <<= 1)
#pragma unroll
        for (int i = 0; i < 8; i++) res[i] += __shfl_xor(res[i], off, 64);
    if (j < 8) {
        int n = nbase + g * 4 + (j >> 1);
        if (n < N_NODES) out[n * 2 + (j & 1)] = res[j] + b2[j & 1];
    }
}

// ----------------------------------------------------------------
extern "C" void kernel_launch(void* const* d_in, const int* in_sizes, int n_in,
                              void* d_out, int out_size, void* d_ws, size_t ws_size,
                              hipStream_t stream) {
    const int* x = (const int*)d_in[0];
    const int* src = (const int*)d_in[1];
    const int* dst = (const int*)d_in[2];
    const float* snorm_n = (const float*)d_in[3];
    // d_in[4] = snorm_e (unused by reference)
    const float* embed = (const float*)d_in[5];
    const float* Ws[3] = {(const float*)d_in[6], (const float*)d_in[11], (const float*)d_in[16]};
    const float* als[3] = {(const float*)d_in[7], (const float*)d_in[12], (const float*)d_in[17]};
    const float* ars[3] = {(const float*)d_in[8], (const float*)d_in[13], (const float*)d_in[18]};
    const float* gms[3] = {(const float*)d_in[9], (const float*)d_in[14], (const float*)d_in[19]};
    const float* bts[3] = {(const float*)d_in[10], (const float*)d_in[15], (const float*)d_in[20]};
    const float* cls1_w = (const float*)d_in[21];
    const float* cls1_b = (const float*)d_in[22];
    const float* cls2_w = (const float*)d_in[23];
    const float* cls2_b = (const float*)d_in[24];
    float* out = (float*)d_out;

    char* ws = (char*)d_ws;
    size_t off = 0;
    auto alloc = [&](size_t bytes) {
        void* p = ws + off;
        off = (off + bytes + 255) & ~(size_t)255;
        return p;
    };
    float* h = (float*)alloc((size_t)N_NODES * HDIM * 4);
    float* feat = (float*)alloc((size_t)N_NODES * HDIM * 4);
    float* el = (float*)alloc((size_t)N_NODES * 4 * 4);
    float* er = (float*)alloc((size_t)N_NODES * 4 * 4);
    int* deg = (int*)alloc((size_t)N_NODES * 4);
    int* rowstart = (int*)alloc((size_t)(N_NODES + 1) * 4);
    int* cursor = (int*)alloc((size_t)N_NODES * 4);
    int* esrc = (int*)alloc((size_t)N_EDGES * 4);
    double* bn_sums = (double*)alloc(256 * 8);
    float* bn_scale = (float*)alloc(128 * 4);
    float* bn_shift = (float*)alloc(128 * 4);
    (void)ws_size; (void)in_sizes; (void)n_in; (void)out_size;

    // CSR by destination (dst constant across layers -> build once per launch)
    hipMemsetAsync(deg, 0, (size_t)N_NODES * 4, stream);
    k_hist<<<(N_EDGES + 255) / 256, 256, 0, stream>>>(dst, deg);
    k_scan<<<1, 1024, 0, stream>>>(deg, rowstart, cursor);
    k_scatter<<<(N_EDGES + 255) / 256, 256, 0, stream>>>(src, dst, cursor, esrc);

    // h0 = embed[x]
    k_embed<<<(N_NODES * HDIM + 255) / 256, 256, 0, stream>>>(x, embed, h);

    for (int L = 0; L < 3; L++) {
        k_gemm<<<(N_NODES + 31) / 32, 256, 0, stream>>>(h, Ws[L], feat);
        k_attn_coef<<<(N_NODES + 3) / 4, 256, 0, stream>>>(feat, als[L], ars[L], el, er);
        k_aggregate<<<(N_NODES + 3) / 4, 256, 0, stream>>>(feat, el, er, rowstart, esrc,
                                                           snorm_n, h, L > 0 ? 1 : 0);
        hipMemsetAsync(bn_sums, 0, 256 * 8, stream);
        k_bn_stats<<<1024, 128, 0, stream>>>(h, bn_sums);
        k_bn_final<<<1, 128, 0, stream>>>(bn_sums, gms[L], bts[L], bn_scale, bn_shift);
        k_bn_apply<<<(N_NODES * 32 + 255) / 256, 256, 0, stream>>>(h, bn_scale, bn_shift);
    }

    k_classifier<<<(N_NODES + 15) / 16, 256, 0, stream>>>(h, cls1_w, cls1_b, cls2_w, cls2_b, out);
}

// Round 2
// 675.201 us; speedup vs baseline: 1.3423x; 1.3423x over previous
//
#include <hip/hip_runtime.h>
#include <hip/hip_bf16.h>
#include <hip/hip_fp16.h>
#include <math.h>

constexpr int N_NODES = 50000;
constexpr int N_EDGES = 850000;
constexpr int HDIM = 128;   // H*D

// ---------------------------------------------------------------- CSR build
__global__ void k_hist(const int* __restrict__ dst, int* __restrict__ deg) {
    int i = blockIdx.x * blockDim.x + threadIdx.x;
    if (i < N_EDGES) atomicAdd(&deg[dst[i]], 1);
}

// single block, 1024 threads (16 waves): wave-shuffle scan of deg -> rowstart, cursor
__global__ void k_scan(const int* __restrict__ deg, int* __restrict__ rowstart,
                       int* __restrict__ cursor) {
    __shared__ int wsum[16];
    __shared__ int s_carry;
    int tid = threadIdx.x, lane = tid & 63, w = tid >> 6;
    if (tid == 0) s_carry = 0;
    for (int base = 0; base < N_NODES; base += 1024) {
        int i = base + tid;
        int v = (i < N_NODES) ? deg[i] : 0;
        int sc = v;  // inclusive scan within wave
#pragma unroll
        for (int off = 1; off < 64; off <<= 1) {
            int t = __shfl_up(sc, off, 64);
            if (lane >= off) sc += t;
        }
        if (lane == 63) wsum[w] = sc;
        __syncthreads();
        int woff = 0;
        for (int j = 0; j < w; j++) woff += wsum[j];
        int carry = s_carry;
        int excl = carry + woff + sc - v;
        if (i < N_NODES) { rowstart[i] = excl; cursor[i] = excl; }
        __syncthreads();
        if (tid == 1023) s_carry = carry + woff + sc;
        __syncthreads();
    }
    if (threadIdx.x == 0) rowstart[N_NODES] = s_carry;
}

__global__ void k_scatter(const int* __restrict__ src, const int* __restrict__ dst,
                          int* __restrict__ cursor, int* __restrict__ esrc) {
    int i = blockIdx.x * blockDim.x + threadIdx.x;
    if (i < N_EDGES) {
        int p = atomicAdd(&cursor[dst[i]], 1);
        esrc[p] = src[i];
    }
}

// ---------------------------------------------------------------- GEMM: feat_h = act(in) @ W  (fp16 out)
// mode 0: in-row n = embed[xidx[n]] (raw). mode 1: in-row n = elu(h[n]*bnsc + bnsh).
// block: 256 thr, 32 nodes/block, 4x4 micro-tile per thread. Input staged transposed in LDS.
__global__ void k_gemm(const float* __restrict__ h, const int* __restrict__ xidx,
                       const float* __restrict__ embed, const float* __restrict__ W,
                       __half* __restrict__ feat_h, const float* __restrict__ bnsc,
                       const float* __restrict__ bnsh, int mode) {
    __shared__ __align__(16) float hsT[128][36];
    int tid = threadIdx.x;
    int nbase = blockIdx.x * 32;
    for (int i = tid; i < 32 * 128; i += 256) {
        int r = i >> 7, c = i & 127;
        int n = nbase + r;
        float v = 0.f;
        if (n < N_NODES) {
            if (mode == 0) {
                v = embed[xidx[n] * HDIM + c];
            } else {
                v = h[n * HDIM + c] * bnsc[c] + bnsh[c];
                v = (v > 0.f) ? v : expm1f(v);
            }
        }
        hsT[c][r] = v;
    }
    __syncthreads();
    int c4 = (tid & 31) * 4;
    int n4 = (tid >> 5) * 4;
    float acc[4][4] = {};
#pragma unroll 4
    for (int k = 0; k < 128; k++) {
        float4 wv4 = *reinterpret_cast<const float4*>(&W[k * HDIM + c4]);
        float4 hv4 = *reinterpret_cast<const float4*>(&hsT[k][n4]);
        float wv[4] = {wv4.x, wv4.y, wv4.z, wv4.w};
        float hh[4] = {hv4.x, hv4.y, hv4.z, hv4.w};
#pragma unroll
        for (int i = 0; i < 4; i++)
#pragma unroll
            for (int j = 0; j < 4; j++) acc[i][j] += hh[i] * wv[j];
    }
#pragma unroll
    for (int i = 0; i < 4; i++) {
        int n = nbase + n4 + i;
        if (n < N_NODES) {
            __half2* p = reinterpret_cast<__half2*>(&feat_h[n * HDIM + c4]);
            p[0] = __floats2half2_rn(acc[i][0], acc[i][1]);
            p[1] = __floats2half2_rn(acc[i][2], acc[i][3]);
        }
    }
}

// ---------------------------------------------------------------- el/er: one wave per node
__global__ void k_attn_coef(const __half* __restrict__ feat_h, const float* __restrict__ al,
                            const float* __restrict__ ar, float* __restrict__ el,
                            float* __restrict__ er) {
    int v = (blockIdx.x * blockDim.x + threadIdx.x) >> 6;
    int lane = threadIdx.x & 63;
    if (v >= N_NODES) return;
    int hd = lane >> 4;
    int d = (lane & 15) * 2;
    float2 f = __half22float2(reinterpret_cast<const __half2*>(feat_h)[v * 64 + lane]);
    float pl = f.x * al[hd * 32 + d] + f.y * al[hd * 32 + d + 1];
    float pr = f.x * ar[hd * 32 + d] + f.y * ar[hd * 32 + d + 1];
#pragma unroll
    for (int off = 1; off < 16; off <<= 1) {
        pl += __shfl_xor(pl, off, 64);
        pr += __shfl_xor(pr, off, 64);
    }
    if ((lane & 15) == 0) {
        el[v * 4 + hd] = pl;
        er[v * 4 + hd] = pr;
    }
}

// ---------------------------------------------------------------- aggregation: one wave per dst node
// single-pass softmax (no max subtraction; e bounded). Residual reads h_pre and applies
// previous layer's BN transform + elu on the fly. Writes h_pre (post-snorm, pre-BN).
__global__ void k_aggregate(const __half* __restrict__ feat_h, const float* __restrict__ el,
                            const float* __restrict__ er, const int* __restrict__ rowstart,
                            const int* __restrict__ esrc, const float* __restrict__ snorm_n,
                            float* __restrict__ h, const float* __restrict__ bnsc,
                            const float* __restrict__ bnsh, int layer) {
    int v = (blockIdx.x * blockDim.x + threadIdx.x) >> 6;
    int lane = threadIdx.x & 63;
    if (v >= N_NODES) return;
    int head = lane >> 4;
    float erv = er[v * 4 + head];
    int e0 = rowstart[v], e1 = rowstart[v + 1];
    float s = 0.f, a0 = 0.f, a1 = 0.f;
    const __half2* fh = reinterpret_cast<const __half2*>(feat_h);
#pragma unroll 4
    for (int i = e0; i < e1; i++) {
        int sidx = esrc[i];
        float e = el[sidx * 4 + head] + erv;
        e = fmaxf(e, 0.f) + 0.2f * fminf(e, 0.f);  // leaky_relu
        float w = __expf(e);
        float2 f = __half22float2(fh[sidx * 64 + lane]);
        s += w;
        a0 = fmaf(f.x, w, a0);
        a1 = fmaf(f.y, w, a1);
    }
    float inv = 1.f / s;  // deg>=1 (self loops)
    a0 *= inv; a1 *= inv;
    int c = lane * 2;
    if (layer > 0) {
        float2 hr = *reinterpret_cast<const float2*>(&h[v * HDIM + c]);
        float2 sc = *reinterpret_cast<const float2*>(&bnsc[c]);
        float2 sh = *reinterpret_cast<const float2*>(&bnsh[c]);
        float r0 = hr.x * sc.x + sh.x; r0 = (r0 > 0.f) ? r0 : expm1f(r0);
        float r1 = hr.y * sc.y + sh.y; r1 = (r1 > 0.f) ? r1 : expm1f(r1);
        a0 += r0; a1 += r1;
        a0 = (a0 > 0.f) ? a0 : expm1f(a0);  // GATConv activation (layers>0)
        a1 = (a1 > 0.f) ? a1 : expm1f(a1);
    }
    float sn = snorm_n[v];
    *reinterpret_cast<float2*>(&h[v * HDIM + c]) = make_float2(a0 * sn, a1 * sn);
}

// ---------------------------------------------------------------- BatchNorm stats
__global__ void k_bn_stats(const float* __restrict__ h, double* __restrict__ sums) {
    int c = threadIdx.x;  // 128 threads: one feature each
    double s = 0.0, s2 = 0.0;
    for (int r = blockIdx.x; r < N_NODES; r += gridDim.x) {
        float v = h[r * HDIM + c];
        s += v;
        s2 += (double)v * v;
    }
    atomicAdd(&sums[c], s);
    atomicAdd(&sums[128 + c], s2);
}

__global__ void k_bn_final(const double* __restrict__ sums, const float* __restrict__ gamma,
                           const float* __restrict__ beta, float* __restrict__ scale,
                           float* __restrict__ shift) {
    int c = threadIdx.x;
    double mu = sums[c] / N_NODES;
    double var = sums[128 + c] / N_NODES - mu * mu;
    float sc = gamma[c] * rsqrtf((float)var + 1e-5f);
    scale[c] = sc;
    shift[c] = beta[c] - (float)mu * sc;
}

// ---------------------------------------------------------------- classifier: relu(act(h)@W1+b1)@W2+b2
// applies final BN transform + elu while staging. 256 thr = 4 waves, 16 nodes/block.
__global__ void k_classifier(const float* __restrict__ h, const float* __restrict__ W1,
                             const float* __restrict__ b1, const float* __restrict__ W2,
                             const float* __restrict__ b2, const float* __restrict__ bnsc,
                             const float* __restrict__ bnsh, float* __restrict__ out) {
    __shared__ float hs[16][128];
    int tid = threadIdx.x;
    int nbase = blockIdx.x * 16;
    for (int i = tid; i < 16 * 128; i += 256) {
        int r = i >> 7, c = i & 127;
        int n = nbase + r;
        float v = 0.f;
        if (n < N_NODES) {
            v = h[n * HDIM + c] * bnsc[c] + bnsh[c];
            v = (v > 0.f) ? v : expm1f(v);
        }
        hs[r][c] = v;
    }
    __syncthreads();
    int j = tid & 63;
    int g = tid >> 6;
    float bj = b1[j];
    float acc[4] = {bj, bj, bj, bj};
    for (int k = 0; k < 128; k++) {
        float w = W1[k * 64 + j];
#pragma unroll
        for (int i = 0; i < 4; i++) acc[i] += hs[g * 4 + i][k] * w;
    }
    float w20 = W2[j * 2], w21 = W2[j * 2 + 1];
    float res[8];
#pragma unroll
    for (int i = 0; i < 4; i++) {
        float hid = fmaxf(acc[i], 0.f);
        res[2 * i] = hid * w20;
        res[2 * i + 1] = hid * w21;
    }
#pragma unroll
    for (int off = 1; off < 64; off <<= 1)
#pragma unroll
        for (int i = 0; i < 8; i++) res[i] += __shfl_xor(res[i], off, 64);
    if (j < 8) {
        int n = nbase + g * 4 + (j >> 1);
        if (n < N_NODES) out[n * 2 + (j & 1)] = res[j] + b2[j & 1];
    }
}

// ----------------------------------------------------------------
extern "C" void kernel_launch(void* const* d_in, const int* in_sizes, int n_in,
                              void* d_out, int out_size, void* d_ws, size_t ws_size,
                              hipStream_t stream) {
    const int* x = (const int*)d_in[0];
    const int* src = (const int*)d_in[1];
    const int* dst = (const int*)d_in[2];
    const float* snorm_n = (const float*)d_in[3];
    const float* embed = (const float*)d_in[5];
    const float* Ws[3] = {(const float*)d_in[6], (const float*)d_in[11], (const float*)d_in[16]};
    const float* als[3] = {(const float*)d_in[7], (const float*)d_in[12], (const float*)d_in[17]};
    const float* ars[3] = {(const float*)d_in[8], (const float*)d_in[13], (const float*)d_in[18]};
    const float* gms[3] = {(const float*)d_in[9], (const float*)d_in[14], (const float*)d_in[19]};
    const float* bts[3] = {(const float*)d_in[10], (const float*)d_in[15], (const float*)d_in[20]};
    const float* cls1_w = (const float*)d_in[21];
    const float* cls1_b = (const float*)d_in[22];
    const float* cls2_w = (const float*)d_in[23];
    const float* cls2_b = (const float*)d_in[24];
    float* out = (float*)d_out;

    char* ws = (char*)d_ws;
    size_t off = 0;
    auto alloc = [&](size_t bytes) {
        void* p = ws + off;
        off = (off + bytes + 255) & ~(size_t)255;
        return p;
    };
    float* h = (float*)alloc((size_t)N_NODES * HDIM * 4);
    __half* feat_h = (__half*)alloc((size_t)N_NODES * HDIM * 2);
    float* el = (float*)alloc((size_t)N_NODES * 4 * 4);
    float* er = (float*)alloc((size_t)N_NODES * 4 * 4);
    int* deg = (int*)alloc((size_t)N_NODES * 4);
    int* rowstart = (int*)alloc((size_t)(N_NODES + 1) * 4);
    int* cursor = (int*)alloc((size_t)N_NODES * 4);
    int* esrc = (int*)alloc((size_t)N_EDGES * 4);
    double* bn_sums = (double*)alloc(256 * 8);
    float* bn_scale = (float*)alloc(128 * 4);
    float* bn_shift = (float*)alloc(128 * 4);
    (void)ws_size; (void)in_sizes; (void)n_in; (void)out_size;

    // CSR by destination (dst constant across layers -> build once per launch)
    hipMemsetAsync(deg, 0, (size_t)N_NODES * 4, stream);
    k_hist<<<(N_EDGES + 255) / 256, 256, 0, stream>>>(dst, deg);
    k_scan<<<1, 1024, 0, stream>>>(deg, rowstart, cursor);
    k_scatter<<<(N_EDGES + 255) / 256, 256, 0, stream>>>(src, dst, cursor, esrc);

    for (int L = 0; L < 3; L++) {
        // gemm fuses: L0 embed gather; L>0 BN transform + elu of previous layer
        k_gemm<<<(N_NODES + 31) / 32, 256, 0, stream>>>(h, x, embed, Ws[L], feat_h,
                                                        bn_scale, bn_shift, L == 0 ? 0 : 1);
        k_attn_coef<<<(N_NODES + 3) / 4, 256, 0, stream>>>(feat_h, als[L], ars[L], el, er);
        k_aggregate<<<(N_NODES + 3) / 4, 256, 0, stream>>>(feat_h, el, er, rowstart, esrc,
                                                           snorm_n, h, bn_scale, bn_shift, L);
        hipMemsetAsync(bn_sums, 0, 256 * 8, stream);
        k_bn_stats<<<1024, 128, 0, stream>>>(h, bn_sums);
        k_bn_final<<<1, 128, 0, stream>>>(bn_sums, gms[L], bts[L], bn_scale, bn_shift);
    }

    k_classifier<<<(N_NODES + 15) / 16, 256, 0, stream>>>(h, cls1_w, cls1_b, cls2_w, cls2_b,
                                                          bn_scale, bn_shift, out);
}